// Round 16
// baseline (1974.199 us; speedup 1.0000x reference)
//
#include <hip/hip_runtime.h>
#include <math.h>

typedef __attribute__((ext_vector_type(8))) __bf16 bf8;
typedef __attribute__((ext_vector_type(4))) __bf16 b4v;
typedef __attribute__((ext_vector_type(4))) float f4;
typedef __attribute__((ext_vector_type(4), aligned(4))) float f4u;   // 4B-aligned vec4 load
typedef __attribute__((ext_vector_type(2), aligned(8))) float f2u;   // 8B-aligned vec2 load

namespace {
constexpr int kB   = 8192;
constexpr int kNP  = 20;
constexpr int kOBS = 17;
constexpr int kACT = 6;
constexpr int kDIN = 23;
constexpr int kH   = 256;
constexpr int kN   = kB * kNP;
constexpr int BM   = 128;   // batch rows per block: 8 batch-tiles; 8 waves x 2 Hcol-tiles
constexpr int NB   = 8;     // batch-tiles per wave (N-dim of swapped MFMA)
constexpr int STR  = 264;   // relay LDS row stride (bf16), rows = batch
constexpr float kLR  = 0.05f;
constexpr float kGAM = (float)(1.0 / (1e-8 + 8.0));
// pack layout per net (shorts): W1p[8192] | W2p[65536] | W2Tp[65536] | Wpp[4096]
constexpr int PACKN = 8192 + 65536 + 65536 + 4096;  // 143360
}

__device__ __forceinline__ short f2bf(float f) {
  unsigned u = __builtin_bit_cast(unsigned, f);
  u = (u + 0x7FFFu + ((u >> 16) & 1u)) >> 16;   // RNE
  return (short)u;
}

// Light barrier: our barriers only order LDS producer->consumer (lgkmcnt traffic).
__device__ __forceinline__ void lbar() {
  asm volatile("s_waitcnt lgkmcnt(0)" ::: "memory");
  __builtin_amdgcn_s_barrier();
  __builtin_amdgcn_sched_barrier(0);
}

// ---------------- init: gather a0, zero logp, cache sum(a0^2) ----------------
__global__ __launch_bounds__(256) void init_kernel(
    const float* __restrict__ a0_table, const int* __restrict__ idx,
    float* __restrict__ a_buf, float* __restrict__ logp_buf,
    float* __restrict__ a0sq_buf)
{
  int n = blockIdx.x * blockDim.x + threadIdx.x;
  if (n >= kN) return;
  int id = idx[n];
  const float* src = a0_table + (size_t)id * kACT;
  float s = 0.f;
  #pragma unroll
  for (int d = 0; d < kACT; ++d) {
    float v = src[d];
    a_buf[(size_t)n * kACT + d] = v;
    s += v * v;
  }
  a0sq_buf[n] = s;
  logp_buf[n] = 0.f;
}

// ---------------- weight packing into MFMA fragment order (once) ----------------
// frag element j of lane l for tile n, k-step kk holds M[kk*32+(l>>4)*8+j][n*16+(l&15)]
// W2T section has W3 folded in: M[k][c] = W3[k] * W2[c][k]
__global__ __launch_bounds__(256) void pack_kernel(
    const float* __restrict__ W1, const float* __restrict__ b1,
    const float* __restrict__ W2, const float* __restrict__ W3,
    short* __restrict__ out)
{
  int i = blockIdx.x * blockDim.x + threadIdx.x;
  if (i >= PACKN) return;
  float v;
  if (i < 8192) {                       // W1 pack: K=32 (23 real + bias row at k=23)
    int t = i;
    int j = t & 7, l = (t >> 3) & 63, n = t >> 9;
    int k = ((l >> 4) << 3) + j, c = (n << 4) + (l & 15);
    v = (k < kDIN) ? W1[k * kH + c] : ((k == kDIN) ? b1[c] : 0.f);
  } else if (i < 8192 + 65536) {        // W2 pack: M[k][c] = W2[k][c]
    int t = i - 8192;
    int j = t & 7, l = (t >> 3) & 63, nk = t >> 9;
    int n = nk & 15, kk = nk >> 4;
    int k = (kk << 5) + ((l >> 4) << 3) + j, c = (n << 4) + (l & 15);
    v = W2[k * kH + c];
  } else if (i < 8192 + 2 * 65536) {    // W2T pack (W3-folded): M[k][c] = W3[k]*W2[c][k]
    int t = i - 8192 - 65536;
    int j = t & 7, l = (t >> 3) & 63, nk = t >> 9;
    int n = nk & 15, kk = nk >> 4;
    int k = (kk << 5) + ((l >> 4) << 3) + j, c = (n << 4) + (l & 15);
    v = W2[c * kH + k] * W3[k];
  } else {                              // proj pack: M[k][d] = W1[17+d][k], d<6
    int t = i - 8192 - 2 * 65536;
    int j = t & 7, l = (t >> 3) & 63, kk = t >> 9;
    int k = (kk << 5) + ((l >> 4) << 3) + j, d = l & 15;
    v = (d < kACT) ? W1[(kOBS + d) * kH + k] : 0.f;
  }
  out[i] = f2bf(v);
}

// ---------------- score = d min(Q1,Q2) / d a ----------------
// Swapped-operand MFMA (weights = A, activations = B). x-fragments built directly
// from global memory (no LDS staging pass, no staging barriers).
__global__ __launch_bounds__(512) void score_mfma(
    const float* __restrict__ obs, const float* __restrict__ a_buf,
    const short* __restrict__ pack0, const short* __restrict__ pack1,
    const float* __restrict__ b2a, const float* __restrict__ W3a, const float* __restrict__ b3a,
    const float* __restrict__ b2b, const float* __restrict__ W3b, const float* __restrict__ b3b,
    float* __restrict__ score)
{
  __shared__ __align__(16) __bf16 hbuf[BM * STR];   // h1 -> mask -> dh1m relay
  __shared__ float qred[8][BM];
  __shared__ float qv_s[2][BM];
  __shared__ float sres[2][BM][8];

  const int tid  = threadIdx.x;
  const int wave = tid >> 6, lane = tid & 63;
  const int g16  = lane >> 4, r15 = lane & 15;
  const int wn   = 2 * wave;           // this wave's first Hcol-tile (of 16)
  const int swz  = r15 & 8;            // relay col XOR (neutral-measured; kept)
  const size_t grow0 = (size_t)blockIdx.x * BM;

  const short* packs[2] = {pack0, pack1};
  const float* b2s[2] = {b2a, b2b};
  const float* W3s[2] = {W3a, W3b};
  const float* b3s[2] = {b3a, b3b};

  const f4 fz = {0.f, 0.f, 0.f, 0.f};
  const __bf16 one_h = (__bf16)1.0f;
  const __bf16 zero_h = (__bf16)0.0f;

#define MM(A, B, C) __builtin_amdgcn_mfma_f32_16x16x32_bf16(A, B, C, 0, 0, 0)
#define AF(nb_, kk_) (*(const bf8*)&hbuf[((nb_) * 16 + r15) * STR + (((kk_) * 32 + g16 * 8) ^ swz)])
#define HW64(nb_, mh_) (*(b4v*)&hbuf[((nb_) * 16 + r15) * STR + ((((wn + (mh_)) * 16) + g16 * 4) ^ swz)])

  #pragma unroll 1
  for (int net = 0; net < 2; ++net) {
    const short* W1p  = packs[net];
    const short* W2p  = W1p + 8192;
    const short* W2Tp = W2p + 65536;
    const short* Wpp  = W2Tp + 65536;
    const float* b2 = b2s[net];
    const float* W3 = W3s[net];
    const float* b3 = b3s[net];

    f4 acc[NB][2];

    // ---- build xa fragments directly from global (x = concat(obs, a, 1, pad)) ----
    bf8 xa[NB];
    #pragma unroll
    for (int nb = 0; nb < NB; ++nb) {
      size_t gr = grow0 + nb * 16 + r15;
      bf8 v;
      if (g16 < 2) {
        const float* p = obs + gr * (size_t)kOBS + g16 * 8;
        f4u lo = *(const f4u*)p;
        f4u hi = *(const f4u*)(p + 4);
        v[0] = (__bf16)lo[0]; v[1] = (__bf16)lo[1]; v[2] = (__bf16)lo[2]; v[3] = (__bf16)lo[3];
        v[4] = (__bf16)hi[0]; v[5] = (__bf16)hi[1]; v[6] = (__bf16)hi[2]; v[7] = (__bf16)hi[3];
      } else if (g16 == 2) {
        float o16 = obs[gr * (size_t)kOBS + 16];
        f4u a03 = *(const f4u*)(a_buf + gr * (size_t)kACT);
        f2u a45 = *(const f2u*)(a_buf + gr * (size_t)kACT + 4);
        v[0] = (__bf16)o16;    v[1] = (__bf16)a03[0]; v[2] = (__bf16)a03[1]; v[3] = (__bf16)a03[2];
        v[4] = (__bf16)a03[3]; v[5] = (__bf16)a45[0]; v[6] = (__bf16)a45[1]; v[7] = one_h;
      } else {
        #pragma unroll
        for (int e = 0; e < 8; ++e) v[e] = zero_h;
      }
      xa[nb] = v;
    }

    // ---- layer 1: h1^T = [W1;b1]^T ·[x,1]^T  (bias folded, C = 0) ----
    {
      bf8 aw0 = *(const bf8*)&W1p[((wn + 0) * 64 + lane) * 8];
      bf8 aw1 = *(const bf8*)&W1p[((wn + 1) * 64 + lane) * 8];
      __builtin_amdgcn_s_setprio(1);
      #pragma unroll
      for (int nb = 0; nb < NB; ++nb) {
        acc[nb][0] = MM(aw0, xa[nb], fz);
        acc[nb][1] = MM(aw1, xa[nb], fz);
      }
      __builtin_amdgcn_s_setprio(0);
    }

    // epilogue: relu, mask bits, h1 -> LDS (b64-contiguous)
    unsigned m1[NB];
    #pragma unroll
    for (int nb = 0; nb < NB; ++nb) m1[nb] = 0u;
    #pragma unroll
    for (int nb = 0; nb < NB; ++nb) {
      #pragma unroll
      for (int mh = 0; mh < 2; ++mh) {
        b4v w;
        #pragma unroll
        for (int rr = 0; rr < 4; ++rr) {
          float h = acc[nb][mh][rr];
          if (h > 0.f) m1[nb] |= (1u << (mh * 4 + rr));
          w[rr] = (__bf16)fmaxf(h, 0.f);
        }
        HW64(nb, mh) = w;
      }
    }
    float4 b2f[2], w3f[2];
    #pragma unroll
    for (int mh = 0; mh < 2; ++mh) {
      b2f[mh] = *(const float4*)&b2[(wn + mh) * 16 + g16 * 4];
      w3f[mh] = *(const float4*)&W3[(wn + mh) * 16 + g16 * 4];
    }
    lbar();                          // bar1: h1 visible

    // ---- layer 2 fwd: h2^T = W2^T · h1^T (kk=0 uses C=0) ----
    {
      bf8 aw0 = *(const bf8*)&W2p[((wn + 0) * 64 + lane) * 8];
      bf8 aw1 = *(const bf8*)&W2p[((wn + 1) * 64 + lane) * 8];
      __builtin_amdgcn_s_setprio(1);
      #pragma unroll
      for (int nb = 0; nb < NB; ++nb) {
        bf8 af = AF(nb, 0);
        acc[nb][0] = MM(aw0, af, fz);
        acc[nb][1] = MM(aw1, af, fz);
      }
      __builtin_amdgcn_s_setprio(0);
    }
    #pragma unroll 2
    for (int kk = 1; kk < 8; ++kk) {
      bf8 aw0 = *(const bf8*)&W2p[((kk * 16 + wn + 0) * 64 + lane) * 8];
      bf8 aw1 = *(const bf8*)&W2p[((kk * 16 + wn + 1) * 64 + lane) * 8];
      __builtin_amdgcn_s_setprio(1);
      #pragma unroll
      for (int nb = 0; nb < NB; ++nb) {
        bf8 af = AF(nb, kk);
        acc[nb][0] = MM(aw0, af, acc[nb][0]);
        acc[nb][1] = MM(aw1, af, acc[nb][1]);
      }
      __builtin_amdgcn_s_setprio(0);
    }
    lbar();                          // bar2: all h1 reads done

    // epilogue: q partials (in-lane over 8 Hcols + 2 shfl) + mask -> LDS (b64)
    #pragma unroll
    for (int nb = 0; nb < NB; ++nb) {
      float qn = 0.f;
      #pragma unroll
      for (int mh = 0; mh < 2; ++mh) {
        b4v w;
        #pragma unroll
        for (int rr = 0; rr < 4; ++rr) {
          float h2 = acc[nb][mh][rr] + b2f[mh][rr];
          bool p = h2 > 0.f;
          qn = fmaf(h2, p ? w3f[mh][rr] : 0.f, qn);
          w[rr] = p ? one_h : zero_h;
        }
        HW64(nb, mh) = w;
      }
      qn += __shfl_xor(qn, 16, 64);
      qn += __shfl_xor(qn, 32, 64);
      if (g16 == 0) qred[wave][nb * 16 + r15] = qn;
    }
    lbar();                          // bar3: mask + qred visible
    if (tid < BM) {
      float q = b3[0];
      #pragma unroll
      for (int w = 0; w < 8; ++w) q += qred[w][tid];
      qv_s[net][tid] = q;
    }

    // ---- layer 2 bwd: dh1^T = (W3-folded W2T)^T · mask^T (kk=0 uses C=0) ----
    {
      bf8 aw0 = *(const bf8*)&W2Tp[((wn + 0) * 64 + lane) * 8];
      bf8 aw1 = *(const bf8*)&W2Tp[((wn + 1) * 64 + lane) * 8];
      __builtin_amdgcn_s_setprio(1);
      #pragma unroll
      for (int nb = 0; nb < NB; ++nb) {
        bf8 af = AF(nb, 0);
        acc[nb][0] = MM(aw0, af, fz);
        acc[nb][1] = MM(aw1, af, fz);
      }
      __builtin_amdgcn_s_setprio(0);
    }
    #pragma unroll 2
    for (int kk = 1; kk < 8; ++kk) {
      bf8 aw0 = *(const bf8*)&W2Tp[((kk * 16 + wn + 0) * 64 + lane) * 8];
      bf8 aw1 = *(const bf8*)&W2Tp[((kk * 16 + wn + 1) * 64 + lane) * 8];
      __builtin_amdgcn_s_setprio(1);
      #pragma unroll
      for (int nb = 0; nb < NB; ++nb) {
        bf8 af = AF(nb, kk);
        acc[nb][0] = MM(aw0, af, acc[nb][0]);
        acc[nb][1] = MM(aw1, af, acc[nb][1]);
      }
      __builtin_amdgcn_s_setprio(0);
    }
    lbar();                          // bar4: all mask reads done

    // epilogue: relu'(h1pre) mask, dh1m -> LDS (b64)
    #pragma unroll
    for (int nb = 0; nb < NB; ++nb) {
      #pragma unroll
      for (int mh = 0; mh < 2; ++mh) {
        b4v w;
        #pragma unroll
        for (int rr = 0; rr < 4; ++rr)
          w[rr] = ((m1[nb] >> (mh * 4 + rr)) & 1u) ? (__bf16)acc[nb][mh][rr] : zero_h;
        HW64(nb, mh) = w;
      }
    }
    lbar();                          // bar5: dh1m visible

    // ---- projection: score^T = W1act^T · dh1m^T; wave owns batch-tile == wave ----
    {
      f4 s = fz;
      __builtin_amdgcn_s_setprio(1);
      #pragma unroll
      for (int kk = 0; kk < 8; ++kk) {
        bf8 aw = *(const bf8*)&Wpp[(kk * 64 + lane) * 8];
        bf8 af = AF(wave, kk);
        s = MM(aw, af, s);
      }
      __builtin_amdgcn_s_setprio(0);
      if (g16 < 2) {
        #pragma unroll
        for (int rr = 0; rr < 4; ++rr) {
          int d = g16 * 4 + rr;
          if (d < kACT) sres[net][wave * 16 + r15][d] = s[rr];
        }
      }
    }
    lbar();                          // bar6: proj reads done before next net's writes
  }

  // select grad of min(q1,q2) per row, coalesced write
  {
    int r = tid >> 2, d4 = tid & 3;
    int sel = (qv_s[0][r] <= qv_s[1][r]) ? 0 : 1;
    #pragma unroll
    for (int pass = 0; pass < 2; ++pass) {
      int d = d4 + pass * 4;
      if (d < kACT)
        score[(grow0 + r) * kACT + d] = sres[sel][r][d];
    }
  }
#undef MM
#undef AF
#undef HW64
}

// ---------------- SVGD particle update (one 32-lane group per batch b) ----------------
__global__ __launch_bounds__(256) void svgd_kernel(
    float* __restrict__ a_buf, const float* __restrict__ score,
    float* __restrict__ logp_buf)
{
  __shared__ float X_s[8 * kNP * kACT];
  __shared__ float S_s[8 * kNP * kACT];
  const int tid = threadIdx.x;
  const size_t base = (size_t)blockIdx.x * 8 * kNP * kACT;
  for (int i = tid; i < 8 * kNP * kACT; i += 256) {
    X_s[i] = a_buf[base + i];
    S_s[i] = score[base + i];
  }
  __syncthreads();
  const int g = tid >> 5, p = tid & 31;
  if (p < kNP) {
    const float* X = X_s + g * kNP * kACT;
    const float* S = S_s + g * kNP * kACT;
    float xp[kACT], phi[kACT];
    #pragma unroll
    for (int d = 0; d < kACT; ++d) { xp[d] = X[p * kACT + d]; phi[d] = 0.f; }
    float t1 = 0.f, t2 = 0.f;
    #pragma unroll 1
    for (int q = 0; q < kNP; ++q) {
      float diff[kACT], d2 = 0.f, dot = 0.f;
      #pragma unroll
      for (int d = 0; d < kACT; ++d) {
        float dd = xp[d] - X[q * kACT + d];
        diff[d] = dd; d2 += dd * dd; dot += dd * S[q * kACT + d];
      }
      float Kv = expf(-kGAM * d2);
      #pragma unroll
      for (int d = 0; d < kACT; ++d)
        phi[d] += Kv * S[q * kACT + d] + 2.f * kGAM * diff[d] * Kv;
      t1 += Kv * dot;
      t2 += 2.f * kGAM * d2 * Kv - (float)kNP * (Kv - (q == p ? 1.f : 0.f));
    }
    size_t n = (size_t)blockIdx.x * 8 * kNP + (size_t)g * kNP + p;
    float term12 = (-2.f * kGAM / (float)kNP) * (t1 + t2);
    logp_buf[n] = logp_buf[n] - kLR * term12;
    #pragma unroll
    for (int d = 0; d < kACT; ++d) {
      float na = xp[d] + kLR * (phi[d] * (1.f / (float)kNP));
      na = fminf(fmaxf(na, -1.f), 1.f);
      a_buf[n * kACT + d] = na;
    }
  }
}

// ---------------- final: tanh + logp assembly ----------------
__global__ __launch_bounds__(256) void final_kernel(
    const float* __restrict__ a_buf, const float* __restrict__ logp_buf,
    const float* __restrict__ a0sq_buf, float* __restrict__ out_a,
    float* __restrict__ out_logp)
{
  const int tid = threadIdx.x;
  const int g = tid >> 5, p = tid & 31;
  const int b = blockIdx.x * 8 + g;
  float lp = 0.f;
  if (p < kNP) {
    size_t n = (size_t)b * kNP + p;
    float lt = 0.f;
    #pragma unroll
    for (int d = 0; d < kACT; ++d) {
      float a = a_buf[n * kACT + d];
      out_a[n * kACT + d] = tanhf(a);
      lt += 2.f * (0.6931471805599453f - a - log1pf(expf(-2.f * a)));
    }
    float lpn = 1.3941240797541021f - 5.f * a0sq_buf[n];
    lp = lpn + logp_buf[n] - lt;
  }
  #pragma unroll
  for (int m = 16; m >= 1; m >>= 1) lp += __shfl_xor(lp, m, 32);
  if (p == 0) out_logp[b] = lp * (1.f / (float)kNP);
}

extern "C" void kernel_launch(void* const* d_in, const int* in_sizes, int n_in,
                              void* d_out, int out_size, void* d_ws, size_t ws_size,
                              hipStream_t stream)
{
  const float* obs  = (const float*)d_in[0];
  const float* a0t  = (const float*)d_in[1];
  const float* q1W1 = (const float*)d_in[2];
  const float* q1b1 = (const float*)d_in[3];
  const float* q1W2 = (const float*)d_in[4];
  const float* q1b2 = (const float*)d_in[5];
  const float* q1W3 = (const float*)d_in[6];
  const float* q1b3 = (const float*)d_in[7];
  const float* q2W1 = (const float*)d_in[8];
  const float* q2b1 = (const float*)d_in[9];
  const float* q2W2 = (const float*)d_in[10];
  const float* q2b2 = (const float*)d_in[11];
  const float* q2W3 = (const float*)d_in[12];
  const float* q2b3 = (const float*)d_in[13];
  const int*   idx  = (const int*)d_in[14];

  float* a_buf   = (float*)d_ws;
  float* score_b = a_buf   + (size_t)kN * kACT;
  float* logp_b  = score_b + (size_t)kN * kACT;
  float* a0sq_b  = logp_b  + kN;
  short* pack0   = (short*)(a0sq_b + kN);
  short* pack1   = pack0 + PACKN;

  float* out_a  = (float*)d_out;
  float* out_lp = out_a + (size_t)kN * kACT;

  init_kernel<<<(kN + 255) / 256, 256, 0, stream>>>(a0t, idx, a_buf, logp_b, a0sq_b);
  pack_kernel<<<(PACKN + 255) / 256, 256, 0, stream>>>(q1W1, q1b1, q1W2, q1W3, pack0);
  pack_kernel<<<(PACKN + 255) / 256, 256, 0, stream>>>(q2W1, q2b1, q2W2, q2W3, pack1);

  for (int t = 0; t < 10; ++t) {
    score_mfma<<<kN / BM, 512, 0, stream>>>(obs, a_buf, pack0, pack1,
        q1b2, q1W3, q1b3, q2b2, q2W3, q2b3, score_b);
    svgd_kernel<<<kB / 8, 256, 0, stream>>>(a_buf, score_b, logp_b);
  }

  final_kernel<<<kB / 8, 256, 0, stream>>>(a_buf, logp_b, a0sq_b, out_a, out_lp);
}

// Round 17
// 1497.467 us; speedup vs baseline: 1.3184x; 1.3184x over previous
//
#include <hip/hip_runtime.h>
#include <math.h>

typedef __attribute__((ext_vector_type(8))) __bf16 bf8;
typedef __attribute__((ext_vector_type(4))) __bf16 b4v;
typedef __attribute__((ext_vector_type(4))) float f4;

namespace {
constexpr int kB   = 8192;
constexpr int kNP  = 20;
constexpr int kOBS = 17;
constexpr int kACT = 6;
constexpr int kDIN = 23;
constexpr int kH   = 256;
constexpr int kN   = kB * kNP;
constexpr int BM   = 128;   // batch rows per block: 8 batch-tiles; 8 waves x 2 Hcol-tiles
constexpr int NB   = 8;     // batch-tiles per wave (N-dim of swapped MFMA)
constexpr int STR  = 264;   // relay LDS row stride (bf16), rows = batch
constexpr int XSTR = 40;    // x staging row stride (overlay in hbuf)
constexpr float kLR  = 0.05f;
constexpr float kGAM = (float)(1.0 / (1e-8 + 8.0));
// pack layout per net (shorts): W1p[8192] | W2p[65536] | W2Tp[65536] | Wpp[4096]
constexpr int PACKN = 8192 + 65536 + 65536 + 4096;  // 143360
}

__device__ __forceinline__ short f2bf(float f) {
  unsigned u = __builtin_bit_cast(unsigned, f);
  u = (u + 0x7FFFu + ((u >> 16) & 1u)) >> 16;   // RNE
  return (short)u;
}

// Light barrier: our barriers only order LDS producer->consumer (lgkmcnt traffic).
__device__ __forceinline__ void lbar() {
  asm volatile("s_waitcnt lgkmcnt(0)" ::: "memory");
  __builtin_amdgcn_s_barrier();
  __builtin_amdgcn_sched_barrier(0);
}

// ---------------- init: gather a0, zero logp, cache sum(a0^2) ----------------
__global__ __launch_bounds__(256) void init_kernel(
    const float* __restrict__ a0_table, const int* __restrict__ idx,
    float* __restrict__ a_buf, float* __restrict__ logp_buf,
    float* __restrict__ a0sq_buf)
{
  int n = blockIdx.x * blockDim.x + threadIdx.x;
  if (n >= kN) return;
  int id = idx[n];
  const float* src = a0_table + (size_t)id * kACT;
  float s = 0.f;
  #pragma unroll
  for (int d = 0; d < kACT; ++d) {
    float v = src[d];
    a_buf[(size_t)n * kACT + d] = v;
    s += v * v;
  }
  a0sq_buf[n] = s;
  logp_buf[n] = 0.f;
}

// ---------------- weight packing into MFMA fragment order (once) ----------------
// frag element j of lane l for tile n, k-step kk holds M[kk*32+(l>>4)*8+j][n*16+(l&15)]
// W2T section has W3 folded in: M[k][c] = W3[k] * W2[c][k]
__global__ __launch_bounds__(256) void pack_kernel(
    const float* __restrict__ W1, const float* __restrict__ b1,
    const float* __restrict__ W2, const float* __restrict__ W3,
    short* __restrict__ out)
{
  int i = blockIdx.x * blockDim.x + threadIdx.x;
  if (i >= PACKN) return;
  float v;
  if (i < 8192) {                       // W1 pack: K=32 (23 real + bias row at k=23)
    int t = i;
    int j = t & 7, l = (t >> 3) & 63, n = t >> 9;
    int k = ((l >> 4) << 3) + j, c = (n << 4) + (l & 15);
    v = (k < kDIN) ? W1[k * kH + c] : ((k == kDIN) ? b1[c] : 0.f);
  } else if (i < 8192 + 65536) {        // W2 pack: M[k][c] = W2[k][c]
    int t = i - 8192;
    int j = t & 7, l = (t >> 3) & 63, nk = t >> 9;
    int n = nk & 15, kk = nk >> 4;
    int k = (kk << 5) + ((l >> 4) << 3) + j, c = (n << 4) + (l & 15);
    v = W2[k * kH + c];
  } else if (i < 8192 + 2 * 65536) {    // W2T pack (W3-folded): M[k][c] = W3[k]*W2[c][k]
    int t = i - 8192 - 65536;
    int j = t & 7, l = (t >> 3) & 63, nk = t >> 9;
    int n = nk & 15, kk = nk >> 4;
    int k = (kk << 5) + ((l >> 4) << 3) + j, c = (n << 4) + (l & 15);
    v = W2[c * kH + k] * W3[k];
  } else {                              // proj pack: M[k][d] = W1[17+d][k], d<6
    int t = i - 8192 - 2 * 65536;
    int j = t & 7, l = (t >> 3) & 63, kk = t >> 9;
    int k = (kk << 5) + ((l >> 4) << 3) + j, d = l & 15;
    v = (d < kACT) ? W1[(kOBS + d) * kH + k] : 0.f;
  }
  out[i] = f2bf(v);
}

// ---------------- score = d min(Q1,Q2) / d a ----------------
// Swapped-operand MFMA (weights = A, activations = B); relay cols XOR-swizzled by
// (r15&8) on BOTH write (b64) and read (b128) sides.
__global__ __launch_bounds__(512) void score_mfma(
    const float* __restrict__ obs, const float* __restrict__ a_buf,
    const short* __restrict__ pack0, const short* __restrict__ pack1,
    const float* __restrict__ b2a, const float* __restrict__ W3a, const float* __restrict__ b3a,
    const float* __restrict__ b2b, const float* __restrict__ W3b, const float* __restrict__ b3b,
    float* __restrict__ score)
{
  __shared__ __align__(16) __bf16 hbuf[BM * STR];   // h1 -> mask -> dh1m (front doubles as x stage)
  __shared__ float qred[8][BM];
  __shared__ float qv_s[2][BM];
  __shared__ float sres[2][BM][8];
  __bf16* xbuf = &hbuf[0];

  const int tid  = threadIdx.x;
  const int wave = tid >> 6, lane = tid & 63;
  const int g16  = lane >> 4, r15 = lane & 15;
  const int wn   = 2 * wave;           // this wave's first Hcol-tile (of 16)
  const int swz  = r15 & 8;            // relay col XOR (bank de-alias)
  const size_t grow0 = (size_t)blockIdx.x * BM;

  const short* packs[2] = {pack0, pack1};
  const float* b2s[2] = {b2a, b2b};
  const float* W3s[2] = {W3a, W3b};
  const float* b3s[2] = {b3a, b3b};

  const f4 fz = {0.f, 0.f, 0.f, 0.f};
  const __bf16 one_h = (__bf16)1.0f;
  const __bf16 zero_h = (__bf16)0.0f;

#define MM(A, B, C) __builtin_amdgcn_mfma_f32_16x16x32_bf16(A, B, C, 0, 0, 0)
#define AF(nb_, kk_) (*(const bf8*)&hbuf[((nb_) * 16 + r15) * STR + (((kk_) * 32 + g16 * 8) ^ swz)])
#define HW64(nb_, mh_) (*(b4v*)&hbuf[((nb_) * 16 + r15) * STR + ((((wn + (mh_)) * 16) + g16 * 4) ^ swz)])

  #pragma unroll 1
  for (int net = 0; net < 2; ++net) {
    const short* W1p  = packs[net];
    const short* W2p  = W1p + 8192;
    const short* W2Tp = W2p + 65536;
    const short* Wpp  = W2Tp + 65536;
    const float* b2 = b2s[net];
    const float* W3 = W3s[net];
    const float* b3 = b3s[net];

    // ---- stage x = concat(obs, a, 1, pad) into overlay ----
    for (int i = tid; i < BM * 32; i += 512) {
      int r = i >> 5, k = i & 31;
      size_t gr = grow0 + r;
      float v = (k < kOBS) ? obs[gr * kOBS + k]
              : ((k < kDIN) ? a_buf[gr * kACT + (k - kOBS)]
              : ((k == kDIN) ? 1.f : 0.f));
      xbuf[r * XSTR + k] = (__bf16)v;
    }
    lbar();                          // x staged

    bf8 xa[NB];
    #pragma unroll
    for (int nb = 0; nb < NB; ++nb)
      xa[nb] = *(const bf8*)&xbuf[(nb * 16 + r15) * XSTR + g16 * 8];
    lbar();                          // xa in regs; overlay may be clobbered

    f4 acc[NB][2];

    // ---- layer 1: h1^T = [W1;b1]^T ·[x,1]^T  (bias folded, C = 0) ----
    {
      bf8 aw0 = *(const bf8*)&W1p[((wn + 0) * 64 + lane) * 8];
      bf8 aw1 = *(const bf8*)&W1p[((wn + 1) * 64 + lane) * 8];
      __builtin_amdgcn_s_setprio(1);
      #pragma unroll
      for (int nb = 0; nb < NB; ++nb) {
        acc[nb][0] = MM(aw0, xa[nb], fz);
        acc[nb][1] = MM(aw1, xa[nb], fz);
      }
      __builtin_amdgcn_s_setprio(0);
    }

    // epilogue: relu, mask bits, h1 -> LDS (b64-contiguous, swizzled)
    unsigned m1[NB];
    #pragma unroll
    for (int nb = 0; nb < NB; ++nb) m1[nb] = 0u;
    #pragma unroll
    for (int nb = 0; nb < NB; ++nb) {
      #pragma unroll
      for (int mh = 0; mh < 2; ++mh) {
        b4v w;
        #pragma unroll
        for (int rr = 0; rr < 4; ++rr) {
          float h = acc[nb][mh][rr];
          if (h > 0.f) m1[nb] |= (1u << (mh * 4 + rr));
          w[rr] = (__bf16)fmaxf(h, 0.f);
        }
        HW64(nb, mh) = w;
      }
    }
    float4 b2f[2], w3f[2];
    #pragma unroll
    for (int mh = 0; mh < 2; ++mh) {
      b2f[mh] = *(const float4*)&b2[(wn + mh) * 16 + g16 * 4];
      w3f[mh] = *(const float4*)&W3[(wn + mh) * 16 + g16 * 4];
    }
    lbar();                          // bar1: h1 visible

    // ---- layer 2 fwd: h2^T = W2^T · h1^T (kk=0 uses C=0) ----
    {
      bf8 aw0 = *(const bf8*)&W2p[((wn + 0) * 64 + lane) * 8];
      bf8 aw1 = *(const bf8*)&W2p[((wn + 1) * 64 + lane) * 8];
      __builtin_amdgcn_s_setprio(1);
      #pragma unroll
      for (int nb = 0; nb < NB; ++nb) {
        bf8 af = AF(nb, 0);
        acc[nb][0] = MM(aw0, af, fz);
        acc[nb][1] = MM(aw1, af, fz);
      }
      __builtin_amdgcn_s_setprio(0);
    }
    #pragma unroll 2
    for (int kk = 1; kk < 8; ++kk) {
      bf8 aw0 = *(const bf8*)&W2p[((kk * 16 + wn + 0) * 64 + lane) * 8];
      bf8 aw1 = *(const bf8*)&W2p[((kk * 16 + wn + 1) * 64 + lane) * 8];
      __builtin_amdgcn_s_setprio(1);
      #pragma unroll
      for (int nb = 0; nb < NB; ++nb) {
        bf8 af = AF(nb, kk);
        acc[nb][0] = MM(aw0, af, acc[nb][0]);
        acc[nb][1] = MM(aw1, af, acc[nb][1]);
      }
      __builtin_amdgcn_s_setprio(0);
    }
    lbar();                          // bar2: all h1 reads done

    // epilogue: q partials (in-lane over 8 Hcols + 2 shfl) + mask -> LDS (b64)
    #pragma unroll
    for (int nb = 0; nb < NB; ++nb) {
      float qn = 0.f;
      #pragma unroll
      for (int mh = 0; mh < 2; ++mh) {
        b4v w;
        #pragma unroll
        for (int rr = 0; rr < 4; ++rr) {
          float h2 = acc[nb][mh][rr] + b2f[mh][rr];
          bool p = h2 > 0.f;
          qn = fmaf(h2, p ? w3f[mh][rr] : 0.f, qn);
          w[rr] = p ? one_h : zero_h;
        }
        HW64(nb, mh) = w;
      }
      qn += __shfl_xor(qn, 16, 64);
      qn += __shfl_xor(qn, 32, 64);
      if (g16 == 0) qred[wave][nb * 16 + r15] = qn;
    }
    lbar();                          // bar3: mask + qred visible
    if (tid < BM) {
      float q = b3[0];
      #pragma unroll
      for (int w = 0; w < 8; ++w) q += qred[w][tid];
      qv_s[net][tid] = q;
    }

    // ---- layer 2 bwd: dh1^T = (W3-folded W2T)^T · mask^T (kk=0 uses C=0) ----
    {
      bf8 aw0 = *(const bf8*)&W2Tp[((wn + 0) * 64 + lane) * 8];
      bf8 aw1 = *(const bf8*)&W2Tp[((wn + 1) * 64 + lane) * 8];
      __builtin_amdgcn_s_setprio(1);
      #pragma unroll
      for (int nb = 0; nb < NB; ++nb) {
        bf8 af = AF(nb, 0);
        acc[nb][0] = MM(aw0, af, fz);
        acc[nb][1] = MM(aw1, af, fz);
      }
      __builtin_amdgcn_s_setprio(0);
    }
    #pragma unroll 2
    for (int kk = 1; kk < 8; ++kk) {
      bf8 aw0 = *(const bf8*)&W2Tp[((kk * 16 + wn + 0) * 64 + lane) * 8];
      bf8 aw1 = *(const bf8*)&W2Tp[((kk * 16 + wn + 1) * 64 + lane) * 8];
      __builtin_amdgcn_s_setprio(1);
      #pragma unroll
      for (int nb = 0; nb < NB; ++nb) {
        bf8 af = AF(nb, kk);
        acc[nb][0] = MM(aw0, af, acc[nb][0]);
        acc[nb][1] = MM(aw1, af, acc[nb][1]);
      }
      __builtin_amdgcn_s_setprio(0);
    }
    lbar();                          // bar4: all mask reads done

    // epilogue: relu'(h1pre) mask, dh1m -> LDS (b64)
    #pragma unroll
    for (int nb = 0; nb < NB; ++nb) {
      #pragma unroll
      for (int mh = 0; mh < 2; ++mh) {
        b4v w;
        #pragma unroll
        for (int rr = 0; rr < 4; ++rr)
          w[rr] = ((m1[nb] >> (mh * 4 + rr)) & 1u) ? (__bf16)acc[nb][mh][rr] : zero_h;
        HW64(nb, mh) = w;
      }
    }
    lbar();                          // bar5: dh1m visible

    // ---- projection: score^T = W1act^T · dh1m^T; wave owns batch-tile == wave ----
    {
      f4 s = fz;
      __builtin_amdgcn_s_setprio(1);
      #pragma unroll
      for (int kk = 0; kk < 8; ++kk) {
        bf8 aw = *(const bf8*)&Wpp[(kk * 64 + lane) * 8];
        bf8 af = AF(wave, kk);
        s = MM(aw, af, s);
      }
      __builtin_amdgcn_s_setprio(0);
      if (g16 < 2) {
        #pragma unroll
        for (int rr = 0; rr < 4; ++rr) {
          int d = g16 * 4 + rr;
          if (d < kACT) sres[net][wave * 16 + r15][d] = s[rr];
        }
      }
    }
    lbar();                          // bar6: proj reads done before next net's writes
  }

  // select grad of min(q1,q2) per row, coalesced write
  {
    int r = tid >> 2, d4 = tid & 3;
    int sel = (qv_s[0][r] <= qv_s[1][r]) ? 0 : 1;
    #pragma unroll
    for (int pass = 0; pass < 2; ++pass) {
      int d = d4 + pass * 4;
      if (d < kACT)
        score[(grow0 + r) * kACT + d] = sres[sel][r][d];
    }
  }
#undef MM
#undef AF
#undef HW64
}

// ---------------- SVGD particle update (one 32-lane group per batch b) ----------------
__global__ __launch_bounds__(256) void svgd_kernel(
    float* __restrict__ a_buf, const float* __restrict__ score,
    float* __restrict__ logp_buf)
{
  __shared__ float X_s[8 * kNP * kACT];
  __shared__ float S_s[8 * kNP * kACT];
  const int tid = threadIdx.x;
  const size_t base = (size_t)blockIdx.x * 8 * kNP * kACT;
  for (int i = tid; i < 8 * kNP * kACT; i += 256) {
    X_s[i] = a_buf[base + i];
    S_s[i] = score[base + i];
  }
  __syncthreads();
  const int g = tid >> 5, p = tid & 31;
  if (p < kNP) {
    const float* X = X_s + g * kNP * kACT;
    const float* S = S_s + g * kNP * kACT;
    float xp[kACT], phi[kACT];
    #pragma unroll
    for (int d = 0; d < kACT; ++d) { xp[d] = X[p * kACT + d]; phi[d] = 0.f; }
    float t1 = 0.f, t2 = 0.f;
    #pragma unroll 1
    for (int q = 0; q < kNP; ++q) {
      float diff[kACT], d2 = 0.f, dot = 0.f;
      #pragma unroll
      for (int d = 0; d < kACT; ++d) {
        float dd = xp[d] - X[q * kACT + d];
        diff[d] = dd; d2 += dd * dd; dot += dd * S[q * kACT + d];
      }
      float Kv = expf(-kGAM * d2);
      #pragma unroll
      for (int d = 0; d < kACT; ++d)
        phi[d] += Kv * S[q * kACT + d] + 2.f * kGAM * diff[d] * Kv;
      t1 += Kv * dot;
      t2 += 2.f * kGAM * d2 * Kv - (float)kNP * (Kv - (q == p ? 1.f : 0.f));
    }
    size_t n = (size_t)blockIdx.x * 8 * kNP + (size_t)g * kNP + p;
    float term12 = (-2.f * kGAM / (float)kNP) * (t1 + t2);
    logp_buf[n] = logp_buf[n] - kLR * term12;
    #pragma unroll
    for (int d = 0; d < kACT; ++d) {
      float na = xp[d] + kLR * (phi[d] * (1.f / (float)kNP));
      na = fminf(fmaxf(na, -1.f), 1.f);
      a_buf[n * kACT + d] = na;
    }
  }
}

// ---------------- final: tanh + logp assembly ----------------
__global__ __launch_bounds__(256) void final_kernel(
    const float* __restrict__ a_buf, const float* __restrict__ logp_buf,
    const float* __restrict__ a0sq_buf, float* __restrict__ out_a,
    float* __restrict__ out_logp)
{
  const int tid = threadIdx.x;
  const int g = tid >> 5, p = tid & 31;
  const int b = blockIdx.x * 8 + g;
  float lp = 0.f;
  if (p < kNP) {
    size_t n = (size_t)b * kNP + p;
    float lt = 0.f;
    #pragma unroll
    for (int d = 0; d < kACT; ++d) {
      float a = a_buf[n * kACT + d];
      out_a[n * kACT + d] = tanhf(a);
      lt += 2.f * (0.6931471805599453f - a - log1pf(expf(-2.f * a)));
    }
    float lpn = 1.3941240797541021f - 5.f * a0sq_buf[n];
    lp = lpn + logp_buf[n] - lt;
  }
  #pragma unroll
  for (int m = 16; m >= 1; m >>= 1) lp += __shfl_xor(lp, m, 32);
  if (p == 0) out_logp[b] = lp * (1.f / (float)kNP);
}

extern "C" void kernel_launch(void* const* d_in, const int* in_sizes, int n_in,
                              void* d_out, int out_size, void* d_ws, size_t ws_size,
                              hipStream_t stream)
{
  const float* obs  = (const float*)d_in[0];
  const float* a0t  = (const float*)d_in[1];
  const float* q1W1 = (const float*)d_in[2];
  const float* q1b1 = (const float*)d_in[3];
  const float* q1W2 = (const float*)d_in[4];
  const float* q1b2 = (const float*)d_in[5];
  const float* q1W3 = (const float*)d_in[6];
  const float* q1b3 = (const float*)d_in[7];
  const float* q2W1 = (const float*)d_in[8];
  const float* q2b1 = (const float*)d_in[9];
  const float* q2W2 = (const float*)d_in[10];
  const float* q2b2 = (const float*)d_in[11];
  const float* q2W3 = (const float*)d_in[12];
  const float* q2b3 = (const float*)d_in[13];
  const int*   idx  = (const int*)d_in[14];

  float* a_buf   = (float*)d_ws;
  float* score_b = a_buf   + (size_t)kN * kACT;
  float* logp_b  = score_b + (size_t)kN * kACT;
  float* a0sq_b  = logp_b  + kN;
  short* pack0   = (short*)(a0sq_b + kN);
  short* pack1   = pack0 + PACKN;

  float* out_a  = (float*)d_out;
  float* out_lp = out_a + (size_t)kN * kACT;

  init_kernel<<<(kN + 255) / 256, 256, 0, stream>>>(a0t, idx, a_buf, logp_b, a0sq_b);
  pack_kernel<<<(PACKN + 255) / 256, 256, 0, stream>>>(q1W1, q1b1, q1W2, q1W3, pack0);
  pack_kernel<<<(PACKN + 255) / 256, 256, 0, stream>>>(q2W1, q2b1, q2W2, q2W3, pack1);

  for (int t = 0; t < 10; ++t) {
    score_mfma<<<kN / BM, 512, 0, stream>>>(obs, a_buf, pack0, pack1,
        q1b2, q1W3, q1b3, q2b2, q2W3, q2b3, score_b);
    svgd_kernel<<<kB / 8, 256, 0, stream>>>(a_buf, score_b, logp_b);
  }

  final_kernel<<<kB / 8, 256, 0, stream>>>(a_buf, logp_b, a0sq_b, out_a, out_lp);
}